// Round 8
// baseline (572.009 us; speedup 1.0000x reference)
//
#include <hip/hip_runtime.h>

typedef float f2 __attribute__((ext_vector_type(2)));

#define PAD 5
#define WSZ 11

// Precomputed normalized 11-tap Gaussian (sigma=1.5).
__device__ __forceinline__ float gw(int k) {
    const float G[WSZ] = {
        0.0010283782f, 0.0075987580f, 0.0360007600f, 0.1093607000f,
        0.2130055600f, 0.2660117400f,
        0.2130055600f, 0.1093607000f, 0.0360007600f, 0.0075987580f, 0.0010283782f };
    return G[k];
}

__global__ __launch_bounds__(64) void init_accum_kernel(double* accum) {
    if (threadIdx.x < 4) accum[threadIdx.x] = 0.0;
}

// Multiwave workgroups of INDEPENDENT 64-lane waves (no __syncthreads) —
// forces high residency at launch (1-wave WGs reached steady state at only
// ~10 waves/CU in R4/R7). Each wave owns a 64-col x RT-row strip.
// Body is the proven R4/R7 pipeline:
//  - depth-2 global prefetch into EXPLICIT SCALAR slots P0/P1 (arrays spilled
//    to scratch in R6: 10x HBM traffic);
//  - horizontal 11-tap via per-wave 74-wide LDS row; fence(wavefront)+
//    wave_barrier pair around the write is REQUIRED (R5: compiler sees no
//    per-thread dependence in cross-lane LDS exchange and reorders);
//  - vertical 11-tap via 12-deep register ring (static indices);
//  - 2x2 avg-pool fused off the staged raw row.
template<int RT, bool PLANAR>
__global__ __launch_bounds__(256, 6) void ssim_scale_kernel(
    const float* __restrict__ img1, const float* __restrict__ img2,
    const f2* __restrict__ pair,
    int H, int W,
    double* __restrict__ accum, int slot,
    f2* __restrict__ pout)
{
    __shared__ f2 st_all[4][80];          // per-wave slice: cols ox-5 .. ox+68
    const int lane = threadIdx.x & 63;
    const int wave = threadIdx.x >> 6;
    const int WPB  = blockDim.x >> 6;
    f2* st = st_all[wave];

    const int ox = (blockIdx.x * WPB + wave) * 64;
    const int r0 = blockIdx.y * RT;
    const int z  = blockIdx.z;
    const size_t base = (size_t)z * H * W;

    constexpr int NIT = RT + 10;
    const float C1 = 1e-4f, C2 = 9e-4f;

    // Per-lane column geometry (iteration-invariant).
    const int c0 = ox - PAD + lane;
    const bool m0 = (c0 >= 0) & (c0 < W);
    const int c0c = min(max(c0, 0), W - 1);
    const int c1 = ox + 59 + lane;                 // halo cols, lanes 0..9
    const bool m1 = (lane < 10) & (c1 < W);
    const int c1c = min(c1, W - 1);

    f2 P0a = {0.f, 0.f}, P0b = {0.f, 0.f};
    f2 P1a = {0.f, 0.f}, P1b = {0.f, 0.f};

    auto issue = [&](int y, f2& A, f2& B) {
        int yc = min(max(y, 0), H - 1);            // clamp; mask at consume
        const size_t roff = base + (size_t)yc * W;
        if (PLANAR) {
            A = (f2){ img1[roff + c0c], img2[roff + c0c] };
            if (lane < 10) B = (f2){ img1[roff + c1c], img2[roff + c1c] };
        } else {
            A = pair[roff + c0c];
            if (lane < 10) B = pair[roff + c1c];
        }
    };

    issue(r0 - PAD + 0, P0a, P0b);
    issue(r0 - PAD + 1, P1a, P1b);

    f2 rmu[12], rsq[12];
    float rxx[12];
    f2 psum = {0.f, 0.f};
    float local = 0.f;
    const f2 zero = {0.f, 0.f};

#pragma clang loop unroll(disable)
    for (int b0 = 0; b0 < NIT; b0 += 12) {
#pragma unroll
        for (int j = 0; j < 12; ++j) {
            const int it = b0 + j;
            if (it < NIT) {
                const int y = r0 - PAD + it;
                const bool yok = (y >= 0) & (y < H);   // wave-uniform

                f2& ca = (j & 1) ? P1a : P0a;          // static slot select
                f2& cb = (j & 1) ? P1b : P0b;
                f2 wa = (yok & m0) ? ca : zero;        // vmcnt wait lands here
                f2 wb = (yok & m1) ? cb : zero;
                issue(y + 2, ca, cb);                  // refill: depth-2 prefetch

                __builtin_amdgcn_fence(__ATOMIC_ACQ_REL, "wavefront");
                __builtin_amdgcn_wave_barrier();
                st[lane] = wa;
                if (lane < 10) st[64 + lane] = wb;
                __builtin_amdgcn_fence(__ATOMIC_ACQ_REL, "wavefront");
                __builtin_amdgcn_wave_barrier();

                // Horizontal 11-tap (cross-lane via LDS; ordering forced above).
                f2 hmu = zero, hsq = zero;
                float hxx = 0.f;
#pragma unroll
                for (int k = 0; k < WSZ; ++k) {
                    f2 p = st[lane + k];
                    hmu += p * gw(k);
                    hsq += (p * p) * gw(k);
                    hxx += (p.x * p.y) * gw(k);
                }
                rmu[it % 12] = hmu;                    // it%12 == j: static
                rsq[it % 12] = hsq;
                rxx[it % 12] = hxx;

                // Fused 2x2 avg-pool from the staged raw row.
                if (pout != nullptr) {
                    const int yt = it - PAD;
                    if ((yt >= 0) & (yt < RT) & (lane < 32)) {
                        f2 s01 = st[PAD + 2 * lane] + st[PAD + 2 * lane + 1];
                        if ((yt & 1) == 0) {
                            psum = s01;
                        } else {
                            f2 m = (psum + s01) * 0.25f;
                            const int Wo = W >> 1;
                            pout[(size_t)z * (H >> 1) * Wo +
                                 (size_t)((r0 + yt) >> 1) * Wo + (ox >> 1) + lane] = m;
                        }
                    }
                }

                // Vertical 11-tap + SSIM.
                if (it >= 10) {
                    f2 vmu = zero, vsq = zero;
                    float vxx = 0.f;
#pragma unroll
                    for (int k = 0; k < WSZ; ++k) {
                        const int s = (j + 2 + k) % 12;  // static after unroll
                        vmu += rmu[s] * gw(k);
                        vsq += rsq[s] * gw(k);
                        vxx += rxx[s] * gw(k);
                    }
                    const float mu1 = vmu.x, mu2 = vmu.y;
                    const float mu11 = mu1 * mu1, mu22 = mu2 * mu2, mu12 = mu1 * mu2;
                    const float sig1 = vsq.x - mu11;
                    const float sig2 = vsq.y - mu22;
                    const float sig12 = vxx - mu12;
                    const float num = (2.f * mu12 + C1) * (2.f * sig12 + C2);
                    const float den = (mu11 + mu22 + C1) * (sig1 + sig2 + C2);
                    local += num * __builtin_amdgcn_rcpf(den);
                }
            }
        }
    }

#pragma unroll
    for (int off = 32; off > 0; off >>= 1) local += __shfl_down(local, off);
    if (lane == 0) atomicAdd(&accum[slot], (double)local);
}

__global__ void finalize_kernel(const double* __restrict__ accum, float* __restrict__ out,
                                double c0, double c1, double c2, double c3)
{
    const double w[4] = {0.0448, 0.2856, 0.3001, 0.2363};
    const double cnt[4] = {c0, c1, c2, c3};
    double loss = 0.0;
#pragma unroll
    for (int s = 0; s < 4; ++s) loss += w[s] * (1.0 - accum[s] / cnt[s]);
    out[0] = (float)loss;
}

extern "C" void kernel_launch(void* const* d_in, const int* in_sizes, int n_in,
                              void* d_out, int out_size, void* d_ws, size_t ws_size,
                              hipStream_t stream) {
    const float* img1 = (const float*)d_in[0];
    const float* img2 = (const float*)d_in[1];
    float* out = (float*)d_out;

    const int H0 = 512, W0 = 512;
    const int NC = in_sizes[0] / (H0 * W0);  // 48

    double* accum = (double*)d_ws;
    f2* p1 = (f2*)((char*)d_ws + 64);                 // NC*256*256
    f2* p2 = p1 + (size_t)NC * 256 * 256;             // NC*128*128
    f2* p3 = p2 + (size_t)NC * 128 * 128;             // NC*64*64

    init_accum_kernel<<<1, 64, 0, stream>>>(accum);

    // Scale 0: RT=32, 4 waves/block (covering 4 x-tiles) -> grid 2x16x48,
    // 6144 waves forced resident in 8-block/CU groups.
    ssim_scale_kernel<32, true><<<dim3(2, 16, NC), 256, 0, stream>>>(
        img1, img2, nullptr, 512, 512, accum, 0, p1);
    // Scale 1: RT=16, 4 waves/block -> 1x16x48, 3072 waves
    ssim_scale_kernel<16, false><<<dim3(1, 16, NC), 256, 0, stream>>>(
        nullptr, nullptr, p1, 256, 256, accum, 1, p2);
    // Scale 2: RT=8, 2 waves/block -> 1x16x48, 1536 waves
    ssim_scale_kernel<8, false><<<dim3(1, 16, NC), 128, 0, stream>>>(
        nullptr, nullptr, p2, 128, 128, accum, 2, p3);
    // Scale 3: RT=4, 1 wave/block -> 1x16x48, 768 waves
    ssim_scale_kernel<4, false><<<dim3(1, 16, NC), 64, 0, stream>>>(
        nullptr, nullptr, p3, 64, 64, accum, 3, nullptr);

    double c0 = (double)NC * 512.0 * 512.0;
    double c1 = (double)NC * 256.0 * 256.0;
    double c2 = (double)NC * 128.0 * 128.0;
    double c3 = (double)NC * 64.0 * 64.0;
    finalize_kernel<<<1, 1, 0, stream>>>(accum, out, c0, c1, c2, c3);
}

// Round 9
// 301.542 us; speedup vs baseline: 1.8969x; 1.8969x over previous
//
#include <hip/hip_runtime.h>

typedef float f2 __attribute__((ext_vector_type(2)));

#define PAD 5
#define WSZ 11

// Pure compiler memory barrier: zero instructions. Orders LDS write vs reads
// at the compiler level; hardware same-wave DS ops execute in order, so no
// waitcnt is needed (unlike fence(ACQ_REL), which may emit drains).
#define COMPILER_MEM_BARRIER() asm volatile("" ::: "memory")

// Precomputed normalized 11-tap Gaussian (sigma=1.5).
__device__ __forceinline__ float gw(int k) {
    const float G[WSZ] = {
        0.0010283782f, 0.0075987580f, 0.0360007600f, 0.1093607000f,
        0.2130055600f, 0.2660117400f,
        0.2130055600f, 0.1093607000f, 0.0360007600f, 0.0075987580f, 0.0010283782f };
    return G[k];
}

__global__ __launch_bounds__(64) void init_accum_kernel(double* accum) {
    if (threadIdx.x < 4) accum[threadIdx.x] = 0.0;
}

// Multiwave workgroups of INDEPENDENT 64-lane waves (no __syncthreads) to
// force residency. NOTE: plain __launch_bounds__(256) — a min-waves second
// arg (R6/R8: (256,6)) capped the allocator at 40 VGPRs and spilled the
// ring/prefetch state to scratch (WRITE_SIZE 25->250 MB, 3x slower).
// Each wave owns a 64-col x RT-row strip, sliding down rows:
//  - depth-2 global prefetch into EXPLICIT SCALAR slots P0/P1 (arrays spill);
//  - horizontal 11-tap via per-wave 74-wide LDS row; compiler barriers around
//    the write are REQUIRED (R5: no per-thread dependence in cross-lane LDS
//    exchange -> compiler reorders) but emit no instructions;
//  - vertical 11-tap via 12-deep register ring (static indices);
//  - 2x2 avg-pool fused off the staged raw row.
template<int RT, bool PLANAR>
__global__ __launch_bounds__(256) void ssim_scale_kernel(
    const float* __restrict__ img1, const float* __restrict__ img2,
    const f2* __restrict__ pair,
    int H, int W,
    double* __restrict__ accum, int slot,
    f2* __restrict__ pout)
{
    __shared__ f2 st_all[4][80];          // per-wave slice: cols ox-5 .. ox+68
    const int lane = threadIdx.x & 63;
    const int wave = threadIdx.x >> 6;
    const int WPB  = blockDim.x >> 6;
    f2* st = st_all[wave];

    const int ox = (blockIdx.x * WPB + wave) * 64;
    const int r0 = blockIdx.y * RT;
    const int z  = blockIdx.z;
    const size_t base = (size_t)z * H * W;

    constexpr int NIT = RT + 10;
    const float C1 = 1e-4f, C2 = 9e-4f;

    // Per-lane column geometry (iteration-invariant).
    const int c0 = ox - PAD + lane;
    const bool m0 = (c0 >= 0) & (c0 < W);
    const int c0c = min(max(c0, 0), W - 1);
    const int c1 = ox + 59 + lane;                 // halo cols, lanes 0..9
    const bool m1 = (lane < 10) & (c1 < W);
    const int c1c = min(c1, W - 1);

    f2 P0a = {0.f, 0.f}, P0b = {0.f, 0.f};
    f2 P1a = {0.f, 0.f}, P1b = {0.f, 0.f};

    auto issue = [&](int y, f2& A, f2& B) {
        int yc = min(max(y, 0), H - 1);            // clamp; mask at consume
        const size_t roff = base + (size_t)yc * W;
        if (PLANAR) {
            A = (f2){ img1[roff + c0c], img2[roff + c0c] };
            if (lane < 10) B = (f2){ img1[roff + c1c], img2[roff + c1c] };
        } else {
            A = pair[roff + c0c];
            if (lane < 10) B = pair[roff + c1c];
        }
    };

    issue(r0 - PAD + 0, P0a, P0b);
    issue(r0 - PAD + 1, P1a, P1b);

    f2 rmu[12], rsq[12];
    float rxx[12];
    f2 psum = {0.f, 0.f};
    float local = 0.f;
    const f2 zero = {0.f, 0.f};

#pragma clang loop unroll(disable)
    for (int b0 = 0; b0 < NIT; b0 += 12) {
#pragma unroll
        for (int j = 0; j < 12; ++j) {
            const int it = b0 + j;
            if (it < NIT) {
                const int y = r0 - PAD + it;
                const bool yok = (y >= 0) & (y < H);   // wave-uniform

                f2& ca = (j & 1) ? P1a : P0a;          // static slot select
                f2& cb = (j & 1) ? P1b : P0b;
                f2 wa = (yok & m0) ? ca : zero;        // vmcnt wait lands here
                f2 wb = (yok & m1) ? cb : zero;
                issue(y + 2, ca, cb);                  // refill: depth-2 prefetch

                COMPILER_MEM_BARRIER();                // write(j) after reads(j-1)
                st[lane] = wa;
                if (lane < 10) st[64 + lane] = wb;
                COMPILER_MEM_BARRIER();                // reads(j) after write(j)

                // Horizontal 11-tap (cross-lane via LDS; HW same-wave order).
                f2 hmu = zero, hsq = zero;
                float hxx = 0.f;
#pragma unroll
                for (int k = 0; k < WSZ; ++k) {
                    f2 p = st[lane + k];
                    hmu += p * gw(k);
                    hsq += (p * p) * gw(k);
                    hxx += (p.x * p.y) * gw(k);
                }
                rmu[it % 12] = hmu;                    // it%12 == j: static
                rsq[it % 12] = hsq;
                rxx[it % 12] = hxx;

                // Fused 2x2 avg-pool from the staged raw row.
                if (pout != nullptr) {
                    const int yt = it - PAD;
                    if ((yt >= 0) & (yt < RT) & (lane < 32)) {
                        f2 s01 = st[PAD + 2 * lane] + st[PAD + 2 * lane + 1];
                        if ((yt & 1) == 0) {
                            psum = s01;
                        } else {
                            f2 m = (psum + s01) * 0.25f;
                            const int Wo = W >> 1;
                            pout[(size_t)z * (H >> 1) * Wo +
                                 (size_t)((r0 + yt) >> 1) * Wo + (ox >> 1) + lane] = m;
                        }
                    }
                }

                // Vertical 11-tap + SSIM.
                if (it >= 10) {
                    f2 vmu = zero, vsq = zero;
                    float vxx = 0.f;
#pragma unroll
                    for (int k = 0; k < WSZ; ++k) {
                        const int s = (j + 2 + k) % 12;  // static after unroll
                        vmu += rmu[s] * gw(k);
                        vsq += rsq[s] * gw(k);
                        vxx += rxx[s] * gw(k);
                    }
                    const float mu1 = vmu.x, mu2 = vmu.y;
                    const float mu11 = mu1 * mu1, mu22 = mu2 * mu2, mu12 = mu1 * mu2;
                    const float sig1 = vsq.x - mu11;
                    const float sig2 = vsq.y - mu22;
                    const float sig12 = vxx - mu12;
                    const float num = (2.f * mu12 + C1) * (2.f * sig12 + C2);
                    const float den = (mu11 + mu22 + C1) * (sig1 + sig2 + C2);
                    local += num * __builtin_amdgcn_rcpf(den);
                }
            }
        }
    }

#pragma unroll
    for (int off = 32; off > 0; off >>= 1) local += __shfl_down(local, off);
    if (lane == 0) atomicAdd(&accum[slot], (double)local);
}

__global__ void finalize_kernel(const double* __restrict__ accum, float* __restrict__ out,
                                double c0, double c1, double c2, double c3)
{
    const double w[4] = {0.0448, 0.2856, 0.3001, 0.2363};
    const double cnt[4] = {c0, c1, c2, c3};
    double loss = 0.0;
#pragma unroll
    for (int s = 0; s < 4; ++s) loss += w[s] * (1.0 - accum[s] / cnt[s]);
    out[0] = (float)loss;
}

extern "C" void kernel_launch(void* const* d_in, const int* in_sizes, int n_in,
                              void* d_out, int out_size, void* d_ws, size_t ws_size,
                              hipStream_t stream) {
    const float* img1 = (const float*)d_in[0];
    const float* img2 = (const float*)d_in[1];
    float* out = (float*)d_out;

    const int H0 = 512, W0 = 512;
    const int NC = in_sizes[0] / (H0 * W0);  // 48

    double* accum = (double*)d_ws;
    f2* p1 = (f2*)((char*)d_ws + 64);                 // NC*256*256
    f2* p2 = p1 + (size_t)NC * 256 * 256;             // NC*128*128
    f2* p3 = p2 + (size_t)NC * 128 * 128;             // NC*64*64

    init_accum_kernel<<<1, 64, 0, stream>>>(accum);

    // Scale 0: RT=32, 4 waves/block -> grid 2x16x48 = 1536 blocks,
    // 6144 waves; ~8 blocks/CU can be resident (2.5 KB LDS, ~64 VGPR).
    ssim_scale_kernel<32, true><<<dim3(2, 16, NC), 256, 0, stream>>>(
        img1, img2, nullptr, 512, 512, accum, 0, p1);
    // Scale 1: RT=16, 4 waves/block -> 1x16x48, 3072 waves
    ssim_scale_kernel<16, false><<<dim3(1, 16, NC), 256, 0, stream>>>(
        nullptr, nullptr, p1, 256, 256, accum, 1, p2);
    // Scale 2: RT=8, 2 waves/block -> 1x16x48, 1536 waves
    ssim_scale_kernel<8, false><<<dim3(1, 16, NC), 128, 0, stream>>>(
        nullptr, nullptr, p2, 128, 128, accum, 2, p3);
    // Scale 3: RT=4, 1 wave/block -> 1x16x48, 768 waves
    ssim_scale_kernel<4, false><<<dim3(1, 16, NC), 64, 0, stream>>>(
        nullptr, nullptr, p3, 64, 64, accum, 3, nullptr);

    double c0 = (double)NC * 512.0 * 512.0;
    double c1 = (double)NC * 256.0 * 256.0;
    double c2 = (double)NC * 128.0 * 128.0;
    double c3 = (double)NC * 64.0 * 64.0;
    finalize_kernel<<<1, 1, 0, stream>>>(accum, out, c0, c1, c2, c3);
}